// Round 2
// baseline (687.888 us; speedup 1.0000x reference)
//
#include <hip/hip_runtime.h>
#include <hip/hip_bf16.h>
#include <cstdint>
#include <cstddef>

typedef short bf16x8 __attribute__((ext_vector_type(8)));
typedef float f32x4 __attribute__((ext_vector_type(4)));

__device__ __forceinline__ void gload_lds16(const void* g, void* l) {
  __builtin_amdgcn_global_load_lds((__attribute__((address_space(1))) const void*)g,
                                   (__attribute__((address_space(3))) void*)l, 16, 0, 0);
}

__device__ __forceinline__ unsigned short f2bf(float f) {
  unsigned u = __builtin_bit_cast(unsigned, f);
  u += 0x7fffu + ((u >> 16) & 1u);
  return (unsigned short)(u >> 16);
}
__device__ __forceinline__ float bf2f(unsigned short h) {
  unsigned u = ((unsigned)h) << 16;
  return __builtin_bit_cast(float, u);
}

// ---------------- cast f32 -> bf16 (vectorized) ----------------
__global__ void k_cast(const float* __restrict__ in, unsigned short* __restrict__ out, int n4) {
  int i = blockIdx.x * blockDim.x + threadIdx.x;
  int stride = gridDim.x * blockDim.x;
  for (; i < n4; i += stride) {
    float4 v = reinterpret_cast<const float4*>(in)[i];
    ushort4 o;
    o.x = f2bf(v.x); o.y = f2bf(v.y); o.z = f2bf(v.z); o.w = f2bf(v.w);
    reinterpret_cast<ushort4*>(out)[i] = o;
  }
}

// ---------------- GEMM: C[M,N] = A[M,K] * B[N,K]^T (bf16 in, f32 acc) ------
__device__ __forceinline__ void storeC(float* C, size_t i, float v) { C[i] = v; }
__device__ __forceinline__ void storeC(unsigned short* C, size_t i, float v) { C[i] = f2bf(v); }

template <typename OutT>
__global__ __launch_bounds__(256) void k_gemm_bt(
    const unsigned short* __restrict__ A,
    const unsigned short* __restrict__ B,
    OutT* __restrict__ C,
    int M, int N, int K) {
  __shared__ __align__(16) unsigned short lA[128 * 64];
  __shared__ __align__(16) unsigned short lB[128 * 64];
  const int tid = threadIdx.x;
  const int w = tid >> 6, l = tid & 63;
  const int m0 = blockIdx.x * 128, n0 = blockIdx.y * 128;
  const int wm = (w >> 1) * 64, wn = (w & 1) * 64;

  f32x4 acc[4][4];
#pragma unroll
  for (int i = 0; i < 4; ++i)
#pragma unroll
    for (int j = 0; j < 4; ++j) acc[i][j] = f32x4{0.f, 0.f, 0.f, 0.f};

  char* lAc = (char*)lA;
  char* lBc = (char*)lB;

  for (int k0 = 0; k0 < K; k0 += 64) {
#pragma unroll
    for (int p = 0; p < 4; ++p) {
      int r = (w * 4 + p) * 8 + (l >> 3);           // tile row 0..127
      int c = (l & 7) ^ (r & 7);                    // pre-swizzled source chunk
      gload_lds16(A + (size_t)(m0 + r) * K + k0 + c * 8, lAc + (w * 4 + p) * 1024);
      gload_lds16(B + (size_t)(n0 + r) * K + k0 + c * 8, lBc + (w * 4 + p) * 1024);
    }
    __syncthreads();
#pragma unroll
    for (int kk = 0; kk < 2; ++kk) {
      bf16x8 af[4], bfr[4];
#pragma unroll
      for (int i = 0; i < 4; ++i) {
        int r = wm + i * 16 + (l & 15);
        int slot = (kk * 4 + (l >> 4)) ^ (r & 7);
        af[i] = *(const bf16x8*)(lAc + r * 128 + slot * 16);
      }
#pragma unroll
      for (int j = 0; j < 4; ++j) {
        int r = wn + j * 16 + (l & 15);
        int slot = (kk * 4 + (l >> 4)) ^ (r & 7);
        bfr[j] = *(const bf16x8*)(lBc + r * 128 + slot * 16);
      }
#pragma unroll
      for (int i = 0; i < 4; ++i)
#pragma unroll
        for (int j = 0; j < 4; ++j)
          acc[i][j] = __builtin_amdgcn_mfma_f32_16x16x32_bf16(af[i], bfr[j], acc[i][j], 0, 0, 0);
    }
    __syncthreads();
  }

#pragma unroll
  for (int i = 0; i < 4; ++i)
#pragma unroll
    for (int j = 0; j < 4; ++j) {
      int row = m0 + wm + i * 16 + (l >> 4) * 4;
      int col = n0 + wn + j * 16 + (l & 15);
#pragma unroll
      for (int r = 0; r < 4; ++r)
        storeC(C, (size_t)(row + r) * N + col, acc[i][j][r]);
    }
}

// ---------------- RoPE on Q in place (+ fold 1/sqrt(HD)) ----------------
__global__ void k_rope_q(unsigned short* __restrict__ q,
                         const float* __restrict__ cosT, const float* __restrict__ sinT) {
  int idx = blockIdx.x * blockDim.x + threadIdx.x;
  if (idx >= 2048 * 32 * 64) return;
  int d0 = idx & 63;
  int h = (idx >> 6) & 31;
  int m = idx >> 11;
  int s = m & 1023;
  unsigned short* row = q + (size_t)m * 4096 + h * 128;
  float a = bf2f(row[d0]), b = bf2f(row[d0 + 64]);
  float c0 = cosT[s * 128 + d0], s0 = sinT[s * 128 + d0];
  float c1 = cosT[s * 128 + d0 + 64], s1 = sinT[s * 128 + d0 + 64];
  const float sc = 0.08838834764831845f;  // 128^-0.5
  row[d0] = f2bf((a * c0 - b * s0) * sc);
  row[d0 + 64] = f2bf((b * c1 + a * s1) * sc);
}

// ---------------- build K: concat(vision,text) + RoPE, head-major ----------
__global__ void k_build_k(const unsigned short* __restrict__ kvlin,  // [2048][1024], k = cols 0..511
                          const unsigned short* __restrict__ vkv,    // [512][1024],  k = cols 0..511
                          const float* __restrict__ cosT, const float* __restrict__ sinT,
                          unsigned short* __restrict__ k_all) {      // [8][1280][128]
  int idx = blockIdx.x * blockDim.x + threadIdx.x;
  if (idx >= 8 * 1280 * 64) return;
  int d0 = idx & 63;
  int t = (idx >> 6) % 1280;
  int bg = idx / (64 * 1280);
  int b = bg >> 2, g = bg & 3;
  float a, bb;
  if (t < 256) {
    const unsigned short* src = vkv + (size_t)(b * 256 + t) * 1024 + g * 128;
    a = bf2f(src[d0]); bb = bf2f(src[d0 + 64]);
  } else {
    const unsigned short* src = kvlin + (size_t)(b * 1024 + t - 256) * 1024 + g * 128;
    a = bf2f(src[d0]); bb = bf2f(src[d0 + 64]);
  }
  float c0 = cosT[t * 128 + d0], s0 = sinT[t * 128 + d0];
  float c1 = cosT[t * 128 + d0 + 64], s1 = sinT[t * 128 + d0 + 64];
  unsigned short* dst = k_all + ((size_t)bg * 1280 + t) * 128;
  dst[d0] = f2bf(a * c0 - bb * s0);
  dst[d0 + 64] = f2bf(bb * c1 + a * s1);
}

// ---------------- build V transposed: [8][128 d][1280 t] ----------------
__global__ void k_build_v(const unsigned short* __restrict__ kvlin,  // v = cols 512..1023
                          const unsigned short* __restrict__ vkv,    // v = cols 512..1023
                          unsigned short* __restrict__ v_t) {
  int idx = blockIdx.x * blockDim.x + threadIdx.x;
  if (idx >= 8 * 128 * 1280) return;
  int t = idx % 1280;
  int d = (idx / 1280) & 127;
  int bg = idx / (1280 * 128);
  int b = bg >> 2, g = bg & 3;
  unsigned short v;
  if (t < 256) v = vkv[(size_t)(b * 256 + t) * 1024 + 512 + g * 128 + d];
  else         v = kvlin[(size_t)(b * 1024 + t - 256) * 1024 + 512 + g * 128 + d];
  v_t[(size_t)bg * 128 * 1280 + (size_t)d * 1280 + t] = v;
}

// ---------------- flash attention: barrier-free, direct global->reg K/V ----
// K and V are L2/L3-resident (K+V per group = 640 KB, FETCH_SIZE showed 25 MB
// total). MFMA B-fragments are contiguous bf16x8 per lane in kall/vt layouts,
// so load them straight from global; the 4 waves of a block read the same tile
// addresses -> L1 hits. No __syncthreads anywhere; lP is wave-private.
__global__ __launch_bounds__(256) void k_attn(
    const unsigned short* __restrict__ qr,     // [2048][4096] roped, pre-scaled
    const unsigned short* __restrict__ k_all,  // [8][1280][128]
    const unsigned short* __restrict__ v_t,    // [8][128][1280]
    unsigned short* __restrict__ attn) {       // [2048][4096]
  __shared__ __align__(16) unsigned short lP[4][16][72];

  const int tid = threadIdx.x, w = tid >> 6, l = tid & 63;
  const int qb = (15 - (int)blockIdx.x) * 64;   // longest-running tiles first
  const int h = blockIdx.y, b = blockIdx.z, g = h >> 3;
  const int bg = b * 4 + g;
  const unsigned short* kg = k_all + (size_t)bg * 1280 * 128;
  const unsigned short* vg = v_t + (size_t)bg * 128 * 1280;

  bf16x8 aq[4];
  {
    int row = qb + w * 16 + (l & 15);
    const unsigned short* p = qr + (size_t)(b * 1024 + row) * 4096 + h * 128 + (l >> 4) * 8;
    aq[0] = *(const bf16x8*)(p);
    aq[1] = *(const bf16x8*)(p + 32);
    aq[2] = *(const bf16x8*)(p + 64);
    aq[3] = *(const bf16x8*)(p + 96);
  }

  f32x4 o[8];
#pragma unroll
  for (int i = 0; i < 8; ++i) o[i] = f32x4{0.f, 0.f, 0.f, 0.f};
  float mr[4] = {-1e30f, -1e30f, -1e30f, -1e30f};
  float lr[4] = {0.f, 0.f, 0.f, 0.f};

  const int qw = qb + w * 16;  // wave's base q row
  int tlim = qb + 320;
  if (tlim > 1280) tlim = 1280;

  for (int t0 = 0; t0 < tlim; t0 += 64) {
    // ---- QK^T: K B-fragments direct from global ----
    f32x4 sfr[4];
#pragma unroll
    for (int sub = 0; sub < 4; ++sub) {
      f32x4 s4 = {0.f, 0.f, 0.f, 0.f};
      const unsigned short* kb = kg + (size_t)(t0 + sub * 16 + (l & 15)) * 128 + (l >> 4) * 8;
#pragma unroll
      for (int kk = 0; kk < 4; ++kk) {
        bf16x8 kf = *(const bf16x8*)(kb + kk * 32);
        s4 = __builtin_amdgcn_mfma_f32_16x16x32_bf16(aq[kk], kf, s4, 0, 0, 0);
      }
      sfr[sub] = s4;
    }

    if (t0 + 63 > qw + 256) {  // wave-uniform: only diagonal tiles mask
#pragma unroll
      for (int sub = 0; sub < 4; ++sub) {
        int t = t0 + sub * 16 + (l & 15);
        int qrow = qw + (l >> 4) * 4;
#pragma unroll
        for (int r = 0; r < 4; ++r)
          if (t > qrow + r + 256) sfr[sub][r] = -1e30f;
      }
    }

    // ---- online softmax ----
    float scl[4], psum[4];
#pragma unroll
    for (int r = 0; r < 4; ++r) {
      float pm = fmaxf(fmaxf(sfr[0][r], sfr[1][r]), fmaxf(sfr[2][r], sfr[3][r]));
      pm = fmaxf(pm, __shfl_xor(pm, 1));
      pm = fmaxf(pm, __shfl_xor(pm, 2));
      pm = fmaxf(pm, __shfl_xor(pm, 4));
      pm = fmaxf(pm, __shfl_xor(pm, 8));
      float mnew = fmaxf(mr[r], pm);
      scl[r] = __expf(mr[r] - mnew);
      mr[r] = mnew;
      psum[r] = 0.f;
    }
#pragma unroll
    for (int sub = 0; sub < 4; ++sub)
#pragma unroll
      for (int r = 0; r < 4; ++r) {
        float p = __expf(sfr[sub][r] - mr[r]);
        psum[r] += p;
        lP[w][(l >> 4) * 4 + r][sub * 16 + (l & 15)] = f2bf(p);
      }
#pragma unroll
    for (int r = 0; r < 4; ++r) {
      float s = psum[r];
      s += __shfl_xor(s, 1);
      s += __shfl_xor(s, 2);
      s += __shfl_xor(s, 4);
      s += __shfl_xor(s, 8);
      lr[r] = lr[r] * scl[r] + s;
    }
#pragma unroll
    for (int cs = 0; cs < 8; ++cs) {
      o[cs][0] *= scl[0]; o[cs][1] *= scl[1];
      o[cs][2] *= scl[2]; o[cs][3] *= scl[3];
    }

    asm volatile("s_waitcnt lgkmcnt(0)" ::: "memory");
    __builtin_amdgcn_sched_barrier(0);

    bf16x8 pa0, pa1;
    {
      const char* pb = (const char*)&lP[w][l & 15][0];
      pa0 = *(const bf16x8*)(pb + (l >> 4) * 16);
      pa1 = *(const bf16x8*)(pb + 64 + (l >> 4) * 16);
    }

    // ---- PV: V B-fragments direct from global ----
#pragma unroll
    for (int cs = 0; cs < 8; ++cs) {
      const unsigned short* vb = vg + (size_t)(cs * 16 + (l & 15)) * 1280 + t0 + (l >> 4) * 8;
      bf16x8 v0 = *(const bf16x8*)(vb);
      bf16x8 v1 = *(const bf16x8*)(vb + 32);
      o[cs] = __builtin_amdgcn_mfma_f32_16x16x32_bf16(pa0, v0, o[cs], 0, 0, 0);
      o[cs] = __builtin_amdgcn_mfma_f32_16x16x32_bf16(pa1, v1, o[cs], 0, 0, 0);
    }
  }

  float inv[4];
#pragma unroll
  for (int r = 0; r < 4; ++r) inv[r] = 1.0f / lr[r];
#pragma unroll
  for (int cs = 0; cs < 8; ++cs)
#pragma unroll
    for (int r = 0; r < 4; ++r) {
      int row = qb + w * 16 + (l >> 4) * 4 + r;
      attn[(size_t)(b * 1024 + row) * 4096 + h * 128 + cs * 16 + (l & 15)] =
          f2bf(o[cs][r] * inv[r]);
    }
}

// ---------------- launcher ----------------
extern "C" void kernel_launch(void* const* d_in, const int* in_sizes, int n_in,
                              void* d_out, int out_size, void* d_ws, size_t ws_size,
                              hipStream_t stream) {
  const float* x    = (const float*)d_in[0];
  const float* vis  = (const float*)d_in[1];
  const float* wq   = (const float*)d_in[2];
  const float* wk   = (const float*)d_in[3];
  const float* wv   = (const float*)d_in[4];
  const float* wo   = (const float*)d_in[5];
  const float* wvkv = (const float*)d_in[6];
  const float* cosT = (const float*)d_in[7];
  const float* sinT = (const float*)d_in[8];
  float* out = (float*)d_out;
  char* ws = (char*)d_ws;

  size_t off = 0;
  auto alloc = [&](size_t b) { size_t r = off; off += (b + 255) & ~(size_t)255; return r; };
  unsigned short* wqb   = (unsigned short*)(ws + alloc((size_t)4096 * 4096 * 2));
  unsigned short* wob   = (unsigned short*)(ws + alloc((size_t)4096 * 4096 * 2));
  unsigned short* wkvb  = (unsigned short*)(ws + alloc((size_t)1024 * 4096 * 2));
  unsigned short* wvkvb = (unsigned short*)(ws + alloc((size_t)1024 * 768 * 2));
  unsigned short* visb  = (unsigned short*)(ws + alloc((size_t)512 * 768 * 2));
  unsigned short* xb    = (unsigned short*)(ws + alloc((size_t)2048 * 4096 * 2));
  unsigned short* qbuf  = (unsigned short*)(ws + alloc((size_t)2048 * 4096 * 2));
  unsigned short* kvlin = (unsigned short*)(ws + alloc((size_t)2048 * 1024 * 2));
  unsigned short* vkvb  = (unsigned short*)(ws + alloc((size_t)512 * 1024 * 2));
  unsigned short* kall  = (unsigned short*)(ws + alloc((size_t)8 * 1280 * 128 * 2));
  unsigned short* vt    = (unsigned short*)(ws + alloc((size_t)8 * 128 * 1280 * 2));
  unsigned short* attnb = xb;  // x is dead after the projections; reuse
  if (ws_size < off) return;

  auto cast = [&](const float* src, unsigned short* dst, size_t n) {
    int n4 = (int)(n / 4);
    int grid = (n4 + 255) / 256;
    if (grid > 1280) grid = 1280;
    k_cast<<<dim3(grid), dim3(256), 0, stream>>>(src, dst, n4);
  };
  cast(x, xb, (size_t)2048 * 4096);
  cast(wq, wqb, (size_t)4096 * 4096);
  cast(wk, wkvb, (size_t)512 * 4096);
  cast(wv, wkvb + (size_t)512 * 4096, (size_t)512 * 4096);
  cast(wo, wob, (size_t)4096 * 4096);
  cast(wvkv, wvkvb, (size_t)1024 * 768);
  cast(vis, visb, (size_t)512 * 768);

  k_gemm_bt<unsigned short><<<dim3(16, 32), dim3(256), 0, stream>>>(xb, wqb, qbuf, 2048, 4096, 4096);
  k_gemm_bt<unsigned short><<<dim3(16, 8), dim3(256), 0, stream>>>(xb, wkvb, kvlin, 2048, 1024, 4096);
  k_gemm_bt<unsigned short><<<dim3(4, 8), dim3(256), 0, stream>>>(visb, wvkvb, vkvb, 512, 1024, 768);

  k_rope_q<<<dim3(16384), dim3(256), 0, stream>>>(qbuf, cosT, sinT);
  k_build_k<<<dim3(2560), dim3(256), 0, stream>>>(kvlin, vkvb, cosT, sinT, kall);
  k_build_v<<<dim3(5120), dim3(256), 0, stream>>>(kvlin, vkvb, vt);

  k_attn<<<dim3(16, 32, 2), dim3(256), 0, stream>>>(qbuf, kall, vt, attnb);

  k_gemm_bt<float><<<dim3(16, 32), dim3(256), 0, stream>>>(attnb, wob, out, 2048, 4096, 4096);
}

// Round 3
// 383.026 us; speedup vs baseline: 1.7959x; 1.7959x over previous
//
#include <hip/hip_runtime.h>
#include <hip/hip_bf16.h>
#include <cstdint>
#include <cstddef>

typedef short bf16x8 __attribute__((ext_vector_type(8)));
typedef float f32x4 __attribute__((ext_vector_type(4)));

__device__ __forceinline__ void gload_lds16(const void* g, void* l) {
  __builtin_amdgcn_global_load_lds((__attribute__((address_space(1))) const void*)g,
                                   (__attribute__((address_space(3))) void*)l, 16, 0, 0);
}

__device__ __forceinline__ unsigned short f2bf(float f) {
  unsigned u = __builtin_bit_cast(unsigned, f);
  u += 0x7fffu + ((u >> 16) & 1u);
  return (unsigned short)(u >> 16);
}
__device__ __forceinline__ float bf2f(unsigned short h) {
  unsigned u = ((unsigned)h) << 16;
  return __builtin_bit_cast(float, u);
}

// ---------------- cast f32 -> bf16 (vectorized) ----------------
__global__ void k_cast(const float* __restrict__ in, unsigned short* __restrict__ out, int n4) {
  int i = blockIdx.x * blockDim.x + threadIdx.x;
  int stride = gridDim.x * blockDim.x;
  for (; i < n4; i += stride) {
    float4 v = reinterpret_cast<const float4*>(in)[i];
    ushort4 o;
    o.x = f2bf(v.x); o.y = f2bf(v.y); o.z = f2bf(v.z); o.w = f2bf(v.w);
    reinterpret_cast<ushort4*>(out)[i] = o;
  }
}

// ---------------- GEMM: C[M,N] = A[M,K] * B[N,K]^T (bf16 in, f32 acc) ------
__device__ __forceinline__ void storeC(float* C, size_t i, float v) { C[i] = v; }
__device__ __forceinline__ void storeC(unsigned short* C, size_t i, float v) { C[i] = f2bf(v); }

template <typename OutT>
__global__ __launch_bounds__(256) void k_gemm_bt(
    const unsigned short* __restrict__ A,
    const unsigned short* __restrict__ B,
    OutT* __restrict__ C,
    int M, int N, int K) {
  __shared__ __align__(16) unsigned short lA[128 * 64];
  __shared__ __align__(16) unsigned short lB[128 * 64];
  const int tid = threadIdx.x;
  const int w = tid >> 6, l = tid & 63;
  // T1: XCD-aware bijective swizzle (all grids here have nwg % 8 == 0)
  const int nwg = gridDim.x * gridDim.y;
  const int orig = blockIdx.y * gridDim.x + blockIdx.x;
  const int cpx = nwg >> 3;
  const int tile = (orig & 7) * cpx + (orig >> 3);
  const int m0 = (tile % gridDim.x) * 128;
  const int n0 = (tile / gridDim.x) * 128;
  const int wm = (w >> 1) * 64, wn = (w & 1) * 64;

  f32x4 acc[4][4];
#pragma unroll
  for (int i = 0; i < 4; ++i)
#pragma unroll
    for (int j = 0; j < 4; ++j) acc[i][j] = f32x4{0.f, 0.f, 0.f, 0.f};

  char* lAc = (char*)lA;
  char* lBc = (char*)lB;

  for (int k0 = 0; k0 < K; k0 += 64) {
#pragma unroll
    for (int p = 0; p < 4; ++p) {
      int r = (w * 4 + p) * 8 + (l >> 3);           // tile row 0..127
      int c = (l & 7) ^ (r & 7);                    // pre-swizzled source chunk
      gload_lds16(A + (size_t)(m0 + r) * K + k0 + c * 8, lAc + (w * 4 + p) * 1024);
      gload_lds16(B + (size_t)(n0 + r) * K + k0 + c * 8, lBc + (w * 4 + p) * 1024);
    }
    __syncthreads();
#pragma unroll
    for (int kk = 0; kk < 2; ++kk) {
      bf16x8 af[4], bfr[4];
#pragma unroll
      for (int i = 0; i < 4; ++i) {
        int r = wm + i * 16 + (l & 15);
        int slot = (kk * 4 + (l >> 4)) ^ (r & 7);
        af[i] = *(const bf16x8*)(lAc + r * 128 + slot * 16);
      }
#pragma unroll
      for (int j = 0; j < 4; ++j) {
        int r = wn + j * 16 + (l & 15);
        int slot = (kk * 4 + (l >> 4)) ^ (r & 7);
        bfr[j] = *(const bf16x8*)(lBc + r * 128 + slot * 16);
      }
#pragma unroll
      for (int i = 0; i < 4; ++i)
#pragma unroll
        for (int j = 0; j < 4; ++j)
          acc[i][j] = __builtin_amdgcn_mfma_f32_16x16x32_bf16(af[i], bfr[j], acc[i][j], 0, 0, 0);
    }
    __syncthreads();
  }

#pragma unroll
  for (int i = 0; i < 4; ++i)
#pragma unroll
    for (int j = 0; j < 4; ++j) {
      int row = m0 + wm + i * 16 + (l >> 4) * 4;
      int col = n0 + wn + j * 16 + (l & 15);
#pragma unroll
      for (int r = 0; r < 4; ++r)
        storeC(C, (size_t)(row + r) * N + col, acc[i][j][r]);
    }
}

// ---------------- RoPE on Q in place (+ fold 1/sqrt(HD)) ----------------
// qkv layout: [2048][5120]; q = cols 0..4095
__global__ void k_rope_q(unsigned short* __restrict__ qkv,
                         const float* __restrict__ cosT, const float* __restrict__ sinT) {
  int idx = blockIdx.x * blockDim.x + threadIdx.x;
  if (idx >= 2048 * 32 * 64) return;
  int d0 = idx & 63;
  int h = (idx >> 6) & 31;
  int m = idx >> 11;
  int s = m & 1023;
  unsigned short* row = qkv + (size_t)m * 5120 + h * 128;
  float a = bf2f(row[d0]), b = bf2f(row[d0 + 64]);
  float c0 = cosT[s * 128 + d0], s0 = sinT[s * 128 + d0];
  float c1 = cosT[s * 128 + d0 + 64], s1 = sinT[s * 128 + d0 + 64];
  const float sc = 0.08838834764831845f;  // 128^-0.5
  row[d0] = f2bf((a * c0 - b * s0) * sc);
  row[d0 + 64] = f2bf((b * c1 + a * s1) * sc);
}

// ---------------- build K: concat(vision,text) + RoPE, head-major ----------
__global__ void k_build_k(const unsigned short* __restrict__ qkv,   // [2048][5120], k = cols 4096..4607
                          const unsigned short* __restrict__ vkv,   // [512][1024],  k = cols 0..511
                          const float* __restrict__ cosT, const float* __restrict__ sinT,
                          unsigned short* __restrict__ k_all) {     // [8][1280][128]
  int idx = blockIdx.x * blockDim.x + threadIdx.x;
  if (idx >= 8 * 1280 * 64) return;
  int d0 = idx & 63;
  int t = (idx >> 6) % 1280;
  int bg = idx / (64 * 1280);
  int b = bg >> 2, g = bg & 3;
  float a, bb;
  if (t < 256) {
    const unsigned short* src = vkv + (size_t)(b * 256 + t) * 1024 + g * 128;
    a = bf2f(src[d0]); bb = bf2f(src[d0 + 64]);
  } else {
    const unsigned short* src = qkv + (size_t)(b * 1024 + t - 256) * 5120 + 4096 + g * 128;
    a = bf2f(src[d0]); bb = bf2f(src[d0 + 64]);
  }
  float c0 = cosT[t * 128 + d0], s0 = sinT[t * 128 + d0];
  float c1 = cosT[t * 128 + d0 + 64], s1 = sinT[t * 128 + d0 + 64];
  unsigned short* dst = k_all + ((size_t)bg * 1280 + t) * 128;
  dst[d0] = f2bf(a * c0 - bb * s0);
  dst[d0 + 64] = f2bf(bb * c1 + a * s1);
}

// ---------------- build V transposed: [8][128 d][1280 t] ----------------
__global__ void k_build_v(const unsigned short* __restrict__ qkv,   // v = cols 4608..5119
                          const unsigned short* __restrict__ vkv,   // v = cols 512..1023
                          unsigned short* __restrict__ v_t) {
  int idx = blockIdx.x * blockDim.x + threadIdx.x;
  if (idx >= 8 * 128 * 1280) return;
  int t = idx % 1280;
  int d = (idx / 1280) & 127;
  int bg = idx / (1280 * 128);
  int b = bg >> 2, g = bg & 3;
  unsigned short v;
  if (t < 256) v = vkv[(size_t)(b * 256 + t) * 1024 + 512 + g * 128 + d];
  else         v = qkv[(size_t)(b * 1024 + t - 256) * 5120 + 4608 + g * 128 + d];
  v_t[(size_t)bg * 128 * 1280 + (size_t)d * 1280 + t] = v;
}

// ---------------- flash attention: LDS-staged, double-buffered pipeline ----
// T3 minimum 2-phase: issue STAGE(buf^1, t+1) BEFORE compute(buf); single
// barrier per iteration so the vmcnt(0) drain lands after compute covered
// the load latency. lP is wave-private -> no extra barrier.
__global__ __launch_bounds__(256) void k_attn(
    const unsigned short* __restrict__ qr,     // [2048][5120] roped, pre-scaled (cols 0..4095)
    const unsigned short* __restrict__ k_all,  // [8][1280][128]
    const unsigned short* __restrict__ v_t,    // [8][128][1280]
    unsigned short* __restrict__ attn) {       // [2048][4096]
  __shared__ __align__(16) unsigned short lK[2][64 * 128];
  __shared__ __align__(16) unsigned short lV[2][128 * 64];
  __shared__ __align__(16) unsigned short lP[4][16][72];

  const int tid = threadIdx.x, w = tid >> 6, l = tid & 63;
  const int qb = (15 - (int)blockIdx.x) * 64;   // longest-running tiles first
  const int h = blockIdx.y, b = blockIdx.z, g = h >> 3;
  const int bg = b * 4 + g;
  const unsigned short* kg = k_all + (size_t)bg * 1280 * 128;
  const unsigned short* vg = v_t + (size_t)bg * 128 * 1280;

  char* lKc = (char*)lK;
  char* lVc = (char*)lV;

  bf16x8 aq[4];
  {
    int row = qb + w * 16 + (l & 15);
    const unsigned short* p = qr + (size_t)(b * 1024 + row) * 5120 + h * 128 + (l >> 4) * 8;
    aq[0] = *(const bf16x8*)(p);
    aq[1] = *(const bf16x8*)(p + 32);
    aq[2] = *(const bf16x8*)(p + 64);
    aq[3] = *(const bf16x8*)(p + 96);
  }

  f32x4 o[8];
#pragma unroll
  for (int i = 0; i < 8; ++i) o[i] = f32x4{0.f, 0.f, 0.f, 0.f};
  float mr[4] = {-1e30f, -1e30f, -1e30f, -1e30f};
  float lr[4] = {0.f, 0.f, 0.f, 0.f};

  const int qw = qb + w * 16;
  int tlim = qb + 320;
  if (tlim > 1280) tlim = 1280;
  const int nIter = tlim >> 6;

  auto stage = [&](int t0, int bufsel) {
#pragma unroll
    for (int p = 0; p < 4; ++p) {  // K tile [64][128]
      int r = (w * 4 + p) * 4 + (l >> 4);
      int c = (l & 15) ^ (r & 7);
      gload_lds16(kg + (size_t)(t0 + r) * 128 + c * 8,
                  lKc + bufsel * 16384 + (w * 4 + p) * 1024);
    }
#pragma unroll
    for (int p = 0; p < 4; ++p) {  // V tile [128][64]
      int d = (w * 4 + p) * 8 + (l >> 3);
      int c = (l & 7) ^ (d & 7);
      gload_lds16(vg + (size_t)d * 1280 + t0 + c * 8,
                  lVc + bufsel * 16384 + (w * 4 + p) * 1024);
    }
  };

  stage(0, 0);
  __syncthreads();

  int buf = 0;
  for (int it = 0; it < nIter; ++it) {
    const int t0 = it << 6;
    if (it + 1 < nIter) stage(t0 + 64, buf ^ 1);  // prefetch next tile

    const char* kbase = lKc + buf * 16384;
    const char* vbase = lVc + buf * 16384;

    f32x4 sfr[4];
#pragma unroll
    for (int sub = 0; sub < 4; ++sub) {
      f32x4 s4 = {0.f, 0.f, 0.f, 0.f};
      int krow = sub * 16 + (l & 15);
      const char* kb = kbase + krow * 256;
#pragma unroll
      for (int kk = 0; kk < 4; ++kk) {
        int slot = (kk * 4 + (l >> 4)) ^ (krow & 7);
        bf16x8 kf = *(const bf16x8*)(kb + slot * 16);
        s4 = __builtin_amdgcn_mfma_f32_16x16x32_bf16(aq[kk], kf, s4, 0, 0, 0);
      }
      sfr[sub] = s4;
    }

    if (t0 + 63 > qw + 256) {  // only diagonal tiles need the mask
#pragma unroll
      for (int sub = 0; sub < 4; ++sub) {
        int t = t0 + sub * 16 + (l & 15);
        int qrow = qw + (l >> 4) * 4;
#pragma unroll
        for (int r = 0; r < 4; ++r)
          if (t > qrow + r + 256) sfr[sub][r] = -1e30f;
      }
    }

    float scl[4], psum[4];
#pragma unroll
    for (int r = 0; r < 4; ++r) {
      float pm = fmaxf(fmaxf(sfr[0][r], sfr[1][r]), fmaxf(sfr[2][r], sfr[3][r]));
      pm = fmaxf(pm, __shfl_xor(pm, 1));
      pm = fmaxf(pm, __shfl_xor(pm, 2));
      pm = fmaxf(pm, __shfl_xor(pm, 4));
      pm = fmaxf(pm, __shfl_xor(pm, 8));
      float mnew = fmaxf(mr[r], pm);
      scl[r] = __expf(mr[r] - mnew);
      mr[r] = mnew;
      psum[r] = 0.f;
    }
#pragma unroll
    for (int sub = 0; sub < 4; ++sub)
#pragma unroll
      for (int r = 0; r < 4; ++r) {
        float p = __expf(sfr[sub][r] - mr[r]);
        psum[r] += p;
        lP[w][(l >> 4) * 4 + r][sub * 16 + (l & 15)] = f2bf(p);
      }
#pragma unroll
    for (int r = 0; r < 4; ++r) {
      float s = psum[r];
      s += __shfl_xor(s, 1);
      s += __shfl_xor(s, 2);
      s += __shfl_xor(s, 4);
      s += __shfl_xor(s, 8);
      lr[r] = lr[r] * scl[r] + s;
    }
#pragma unroll
    for (int cs = 0; cs < 8; ++cs) {
      o[cs][0] *= scl[0]; o[cs][1] *= scl[1];
      o[cs][2] *= scl[2]; o[cs][3] *= scl[3];
    }

    asm volatile("s_waitcnt lgkmcnt(0)" ::: "memory");
    __builtin_amdgcn_sched_barrier(0);

    bf16x8 pa0, pa1;
    {
      const char* pb = (const char*)&lP[w][l & 15][0];
      pa0 = *(const bf16x8*)(pb + (l >> 4) * 16);
      pa1 = *(const bf16x8*)(pb + 64 + (l >> 4) * 16);
    }
#pragma unroll
    for (int cs = 0; cs < 8; ++cs) {
      int drow = cs * 16 + (l & 15);
      const char* vb = vbase + drow * 128;
      int s0 = ((l >> 4)) ^ (drow & 7);
      int s1 = (4 + (l >> 4)) ^ (drow & 7);
      bf16x8 v0 = *(const bf16x8*)(vb + s0 * 16);
      bf16x8 v1 = *(const bf16x8*)(vb + s1 * 16);
      o[cs] = __builtin_amdgcn_mfma_f32_16x16x32_bf16(pa0, v0, o[cs], 0, 0, 0);
      o[cs] = __builtin_amdgcn_mfma_f32_16x16x32_bf16(pa1, v1, o[cs], 0, 0, 0);
    }

    __syncthreads();  // single drain per iteration (covers next-tile stage)
    buf ^= 1;
  }

  float inv[4];
#pragma unroll
  for (int r = 0; r < 4; ++r) inv[r] = 1.0f / lr[r];
#pragma unroll
  for (int cs = 0; cs < 8; ++cs)
#pragma unroll
    for (int r = 0; r < 4; ++r) {
      int row = qb + w * 16 + (l >> 4) * 4 + r;
      attn[(size_t)(b * 1024 + row) * 4096 + h * 128 + cs * 16 + (l & 15)] =
          f2bf(o[cs][r] * inv[r]);
    }
}

// ---------------- launcher ----------------
extern "C" void kernel_launch(void* const* d_in, const int* in_sizes, int n_in,
                              void* d_out, int out_size, void* d_ws, size_t ws_size,
                              hipStream_t stream) {
  const float* x    = (const float*)d_in[0];
  const float* vis  = (const float*)d_in[1];
  const float* wq   = (const float*)d_in[2];
  const float* wk   = (const float*)d_in[3];
  const float* wv   = (const float*)d_in[4];
  const float* wo   = (const float*)d_in[5];
  const float* wvkv = (const float*)d_in[6];
  const float* cosT = (const float*)d_in[7];
  const float* sinT = (const float*)d_in[8];
  float* out = (float*)d_out;
  char* ws = (char*)d_ws;

  size_t off = 0;
  auto alloc = [&](size_t b) { size_t r = off; off += (b + 255) & ~(size_t)255; return r; };
  unsigned short* wqkvb = (unsigned short*)(ws + alloc((size_t)5120 * 4096 * 2));  // wq|wk|wv
  unsigned short* wob   = (unsigned short*)(ws + alloc((size_t)4096 * 4096 * 2));
  unsigned short* wvkvb = (unsigned short*)(ws + alloc((size_t)1024 * 768 * 2));
  unsigned short* visb  = (unsigned short*)(ws + alloc((size_t)512 * 768 * 2));
  unsigned short* xb    = (unsigned short*)(ws + alloc((size_t)2048 * 4096 * 2));
  unsigned short* qkv   = (unsigned short*)(ws + alloc((size_t)2048 * 5120 * 2));
  unsigned short* vkvb  = (unsigned short*)(ws + alloc((size_t)512 * 1024 * 2));
  unsigned short* kall  = (unsigned short*)(ws + alloc((size_t)8 * 1280 * 128 * 2));
  unsigned short* vt    = (unsigned short*)(ws + alloc((size_t)8 * 128 * 1280 * 2));
  unsigned short* attnb = xb;  // x is dead after the QKV projection; reuse
  if (ws_size < off) return;

  auto cast = [&](const float* src, unsigned short* dst, size_t n) {
    int n4 = (int)(n / 4);
    int grid = (n4 + 255) / 256;
    if (grid > 1280) grid = 1280;
    k_cast<<<dim3(grid), dim3(256), 0, stream>>>(src, dst, n4);
  };
  cast(x, xb, (size_t)2048 * 4096);
  cast(wq, wqkvb, (size_t)4096 * 4096);
  cast(wk, wqkvb + (size_t)4096 * 4096, (size_t)512 * 4096);
  cast(wv, wqkvb + (size_t)4608 * 4096, (size_t)512 * 4096);
  cast(wo, wob, (size_t)4096 * 4096);
  cast(wvkv, wvkvb, (size_t)1024 * 768);
  cast(vis, visb, (size_t)512 * 768);

  // fused QKV projection: [2048][5120]
  k_gemm_bt<unsigned short><<<dim3(16, 40), dim3(256), 0, stream>>>(xb, wqkvb, qkv, 2048, 5120, 4096);
  k_gemm_bt<unsigned short><<<dim3(4, 8), dim3(256), 0, stream>>>(visb, wvkvb, vkvb, 512, 1024, 768);

  k_rope_q<<<dim3(16384), dim3(256), 0, stream>>>(qkv, cosT, sinT);
  k_build_k<<<dim3(2560), dim3(256), 0, stream>>>(qkv, vkvb, cosT, sinT, kall);
  k_build_v<<<dim3(5120), dim3(256), 0, stream>>>(qkv, vkvb, vt);

  k_attn<<<dim3(16, 32, 2), dim3(256), 0, stream>>>(qkv, kall, vt, attnb);

  k_gemm_bt<float><<<dim3(16, 32), dim3(256), 0, stream>>>(attnb, wob, out, 2048, 4096, 4096);
}

// Round 4
// 358.616 us; speedup vs baseline: 1.9182x; 1.0681x over previous
//
#include <hip/hip_runtime.h>
#include <hip/hip_bf16.h>
#include <cstdint>
#include <cstddef>

typedef short bf16x8 __attribute__((ext_vector_type(8)));
typedef float f32x4 __attribute__((ext_vector_type(4)));

__device__ __forceinline__ void gload_lds16(const void* g, void* l) {
  __builtin_amdgcn_global_load_lds((__attribute__((address_space(1))) const void*)g,
                                   (__attribute__((address_space(3))) void*)l, 16, 0, 0);
}

__device__ __forceinline__ unsigned short f2bf(float f) {
  unsigned u = __builtin_bit_cast(unsigned, f);
  u += 0x7fffu + ((u >> 16) & 1u);
  return (unsigned short)(u >> 16);
}
__device__ __forceinline__ float bf2f(unsigned short h) {
  unsigned u = ((unsigned)h) << 16;
  return __builtin_bit_cast(float, u);
}

// ---------------- cast f32 -> bf16 (vectorized) ----------------
__global__ void k_cast(const float* __restrict__ in, unsigned short* __restrict__ out, int n4) {
  int i = blockIdx.x * blockDim.x + threadIdx.x;
  int stride = gridDim.x * blockDim.x;
  for (; i < n4; i += stride) {
    float4 v = reinterpret_cast<const float4*>(in)[i];
    ushort4 o;
    o.x = f2bf(v.x); o.y = f2bf(v.y); o.z = f2bf(v.z); o.w = f2bf(v.w);
    reinterpret_cast<ushort4*>(out)[i] = o;
  }
}

// ---------------- GEMM: C[M,N] = A[M,K] * B[N,K]^T (bf16 in, f32 acc) ------
__device__ __forceinline__ void storeC(float* C, size_t i, float v) { C[i] = v; }
__device__ __forceinline__ void storeC(unsigned short* C, size_t i, float v) { C[i] = f2bf(v); }

template <typename OutT>
__global__ __launch_bounds__(256) void k_gemm_bt(
    const unsigned short* __restrict__ A,
    const unsigned short* __restrict__ B,
    OutT* __restrict__ C,
    int M, int N, int K) {
  __shared__ __align__(16) unsigned short lA[128 * 64];
  __shared__ __align__(16) unsigned short lB[128 * 64];
  const int tid = threadIdx.x;
  const int w = tid >> 6, l = tid & 63;
  // T1: XCD-aware bijective swizzle (all grids here have nwg % 8 == 0)
  const int nwg = gridDim.x * gridDim.y;
  const int orig = blockIdx.y * gridDim.x + blockIdx.x;
  const int cpx = nwg >> 3;
  const int tile = (orig & 7) * cpx + (orig >> 3);
  const int m0 = (tile % gridDim.x) * 128;
  const int n0 = (tile / gridDim.x) * 128;
  const int wm = (w >> 1) * 64, wn = (w & 1) * 64;

  f32x4 acc[4][4];
#pragma unroll
  for (int i = 0; i < 4; ++i)
#pragma unroll
    for (int j = 0; j < 4; ++j) acc[i][j] = f32x4{0.f, 0.f, 0.f, 0.f};

  char* lAc = (char*)lA;
  char* lBc = (char*)lB;

  for (int k0 = 0; k0 < K; k0 += 64) {
#pragma unroll
    for (int p = 0; p < 4; ++p) {
      int r = (w * 4 + p) * 8 + (l >> 3);           // tile row 0..127
      int c = (l & 7) ^ (r & 7);                    // pre-swizzled source chunk
      gload_lds16(A + (size_t)(m0 + r) * K + k0 + c * 8, lAc + (w * 4 + p) * 1024);
      gload_lds16(B + (size_t)(n0 + r) * K + k0 + c * 8, lBc + (w * 4 + p) * 1024);
    }
    __syncthreads();
#pragma unroll
    for (int kk = 0; kk < 2; ++kk) {
      bf16x8 af[4], bfr[4];
#pragma unroll
      for (int i = 0; i < 4; ++i) {
        int r = wm + i * 16 + (l & 15);
        int slot = (kk * 4 + (l >> 4)) ^ (r & 7);
        af[i] = *(const bf16x8*)(lAc + r * 128 + slot * 16);
      }
#pragma unroll
      for (int j = 0; j < 4; ++j) {
        int r = wn + j * 16 + (l & 15);
        int slot = (kk * 4 + (l >> 4)) ^ (r & 7);
        bfr[j] = *(const bf16x8*)(lBc + r * 128 + slot * 16);
      }
#pragma unroll
      for (int i = 0; i < 4; ++i)
#pragma unroll
        for (int j = 0; j < 4; ++j)
          acc[i][j] = __builtin_amdgcn_mfma_f32_16x16x32_bf16(af[i], bfr[j], acc[i][j], 0, 0, 0);
    }
    __syncthreads();
  }

#pragma unroll
  for (int i = 0; i < 4; ++i)
#pragma unroll
    for (int j = 0; j < 4; ++j) {
      int row = m0 + wm + i * 16 + (l >> 4) * 4;
      int col = n0 + wn + j * 16 + (l & 15);
#pragma unroll
      for (int r = 0; r < 4; ++r)
        storeC(C, (size_t)(row + r) * N + col, acc[i][j][r]);
    }
}

// ---------------- RoPE on Q in place (+ fold 1/sqrt(HD)) ----------------
// qkv layout: [2048][5120]; q = cols 0..4095
__global__ void k_rope_q(unsigned short* __restrict__ qkv,
                         const float* __restrict__ cosT, const float* __restrict__ sinT) {
  int idx = blockIdx.x * blockDim.x + threadIdx.x;
  if (idx >= 2048 * 32 * 64) return;
  int d0 = idx & 63;
  int h = (idx >> 6) & 31;
  int m = idx >> 11;
  int s = m & 1023;
  unsigned short* row = qkv + (size_t)m * 5120 + h * 128;
  float a = bf2f(row[d0]), b = bf2f(row[d0 + 64]);
  float c0 = cosT[s * 128 + d0], s0 = sinT[s * 128 + d0];
  float c1 = cosT[s * 128 + d0 + 64], s1 = sinT[s * 128 + d0 + 64];
  const float sc = 0.08838834764831845f;  // 128^-0.5
  row[d0] = f2bf((a * c0 - b * s0) * sc);
  row[d0 + 64] = f2bf((b * c1 + a * s1) * sc);
}

// ---------------- build K: concat(vision,text) + RoPE, head-major ----------
__global__ void k_build_k(const unsigned short* __restrict__ qkv,   // [2048][5120], k = cols 4096..4607
                          const unsigned short* __restrict__ vkv,   // [512][1024],  k = cols 0..511
                          const float* __restrict__ cosT, const float* __restrict__ sinT,
                          unsigned short* __restrict__ k_all) {     // [8][1280][128]
  int idx = blockIdx.x * blockDim.x + threadIdx.x;
  if (idx >= 8 * 1280 * 64) return;
  int d0 = idx & 63;
  int t = (idx >> 6) % 1280;
  int bg = idx / (64 * 1280);
  int b = bg >> 2, g = bg & 3;
  float a, bb;
  if (t < 256) {
    const unsigned short* src = vkv + (size_t)(b * 256 + t) * 1024 + g * 128;
    a = bf2f(src[d0]); bb = bf2f(src[d0 + 64]);
  } else {
    const unsigned short* src = qkv + (size_t)(b * 1024 + t - 256) * 5120 + 4096 + g * 128;
    a = bf2f(src[d0]); bb = bf2f(src[d0 + 64]);
  }
  float c0 = cosT[t * 128 + d0], s0 = sinT[t * 128 + d0];
  float c1 = cosT[t * 128 + d0 + 64], s1 = sinT[t * 128 + d0 + 64];
  unsigned short* dst = k_all + ((size_t)bg * 1280 + t) * 128;
  dst[d0] = f2bf(a * c0 - bb * s0);
  dst[d0 + 64] = f2bf(bb * c1 + a * s1);
}

// ---------------- build V transposed: [8][128 d][1280 t] ----------------
__global__ void k_build_v(const unsigned short* __restrict__ qkv,   // v = cols 4608..5119
                          const unsigned short* __restrict__ vkv,   // v = cols 512..1023
                          unsigned short* __restrict__ v_t) {
  int idx = blockIdx.x * blockDim.x + threadIdx.x;
  if (idx >= 8 * 128 * 1280) return;
  int t = idx % 1280;
  int d = (idx / 1280) & 127;
  int bg = idx / (1280 * 128);
  int b = bg >> 2, g = bg & 3;
  unsigned short v;
  if (t < 256) v = vkv[(size_t)(b * 256 + t) * 1024 + 512 + g * 128 + d];
  else         v = qkv[(size_t)(b * 1024 + t - 256) * 5120 + 4608 + g * 128 + d];
  v_t[(size_t)bg * 128 * 1280 + (size_t)d * 1280 + t] = v;
}

// ---------------- flash attention: swapped QK^T + in-register softmax ------
// mfma(K,Q) gives S^T: each lane owns 16 scores of ONE q-row (col = l&15).
// Row-max: fmax tree + 2 shuffles. lr: per-lane partial, reduced once at end.
// Defer-max (THR=8) skips o-rescale on most iters. P goes back to A-frag
// layout via a 2KB/wave LDS transpose (4x ds_write_b64 + 2x ds_read_b128,
// XOR-swizzled, wave-private -> waitcnt only, no barrier).
__global__ __launch_bounds__(256) void k_attn(
    const unsigned short* __restrict__ qr,     // [2048][5120] roped, pre-scaled (cols 0..4095)
    const unsigned short* __restrict__ k_all,  // [8][1280][128]
    const unsigned short* __restrict__ v_t,    // [8][128][1280]
    unsigned short* __restrict__ attn) {       // [2048][4096]
  __shared__ __align__(16) unsigned short lK[2][64 * 128];
  __shared__ __align__(16) unsigned short lV[2][128 * 64];
  __shared__ __align__(16) unsigned short lPT[4][16][64];

  const int tid = threadIdx.x, w = tid >> 6, l = tid & 63;
  const int lq = l & 15, g = l >> 4;
  const int qb = (15 - (int)blockIdx.x) * 64;   // longest-running tiles first
  const int h = blockIdx.y, b = blockIdx.z;
  const int bg = b * 4 + (h >> 3);
  const unsigned short* kg = k_all + (size_t)bg * 1280 * 128;
  const unsigned short* vg = v_t + (size_t)bg * 128 * 1280;

  char* lKc = (char*)lK;
  char* lVc = (char*)lV;
  char* pbuf = (char*)&lPT[w][0][0];

  bf16x8 aq[4];
  {
    int row = qb + w * 16 + lq;
    const unsigned short* p = qr + (size_t)(b * 1024 + row) * 5120 + h * 128 + g * 8;
    aq[0] = *(const bf16x8*)(p);
    aq[1] = *(const bf16x8*)(p + 32);
    aq[2] = *(const bf16x8*)(p + 64);
    aq[3] = *(const bf16x8*)(p + 96);
  }

  f32x4 o[8];
#pragma unroll
  for (int i = 0; i < 8; ++i) o[i] = f32x4{0.f, 0.f, 0.f, 0.f};
  float mr = -1e30f;   // running max for q-row (qb + w*16 + lq)
  float lrp = 0.f;     // per-lane partial sum for that q-row

  const int qrow_l = qb + w * 16 + lq;
  int tlim = qb + 320;
  if (tlim > 1280) tlim = 1280;
  const int nIter = tlim >> 6;

  auto stage = [&](int t0, int bufsel) {
#pragma unroll
    for (int p = 0; p < 4; ++p) {  // K tile [64][128]
      int r = (w * 4 + p) * 4 + (l >> 4);
      int c = (l & 15) ^ (r & 7);
      gload_lds16(kg + (size_t)(t0 + r) * 128 + c * 8,
                  lKc + bufsel * 16384 + (w * 4 + p) * 1024);
    }
#pragma unroll
    for (int p = 0; p < 4; ++p) {  // V tile [128][64]
      int d = (w * 4 + p) * 8 + (l >> 3);
      int c = (l & 7) ^ (d & 7);
      gload_lds16(vg + (size_t)d * 1280 + t0 + c * 8,
                  lVc + bufsel * 16384 + (w * 4 + p) * 1024);
    }
  };

  stage(0, 0);
  __syncthreads();

  int buf = 0;
  for (int it = 0; it < nIter; ++it) {
    const int t0 = it << 6;
    if (it + 1 < nIter) stage(t0 + 64, buf ^ 1);  // prefetch next tile

    const char* kbase = lKc + buf * 16384;
    const char* vbase = lVc + buf * 16384;

    // ---- QK^T swapped: sT[sub][r] = S[t = t0+16*sub+4*g+r][q = qb+w*16+lq]
    f32x4 sT[4];
#pragma unroll
    for (int sub = 0; sub < 4; ++sub) {
      f32x4 s4 = {0.f, 0.f, 0.f, 0.f};
      int krow = sub * 16 + lq;
      const char* kb = kbase + krow * 256;
#pragma unroll
      for (int kk = 0; kk < 4; ++kk) {
        int slot = (kk * 4 + g) ^ (krow & 7);
        bf16x8 kf = *(const bf16x8*)(kb + slot * 16);
        s4 = __builtin_amdgcn_mfma_f32_16x16x32_bf16(kf, aq[kk], s4, 0, 0, 0);
      }
      sT[sub] = s4;
    }

    if (t0 + 63 > qb + w * 16 + 256) {  // only diagonal tiles need the mask
#pragma unroll
      for (int sub = 0; sub < 4; ++sub)
#pragma unroll
        for (int r = 0; r < 4; ++r) {
          int t = t0 + sub * 16 + 4 * g + r;
          if (t > qrow_l + 256) sT[sub][r] = -1e30f;
        }
    }

    // ---- in-register softmax for this lane's q-row ----
    float pm = fmaxf(fmaxf(fmaxf(sT[0][0], sT[0][1]), fmaxf(sT[0][2], sT[0][3])),
                     fmaxf(fmaxf(sT[1][0], sT[1][1]), fmaxf(sT[1][2], sT[1][3])));
    pm = fmaxf(pm, fmaxf(fmaxf(fmaxf(sT[2][0], sT[2][1]), fmaxf(sT[2][2], sT[2][3])),
                         fmaxf(fmaxf(sT[3][0], sT[3][1]), fmaxf(sT[3][2], sT[3][3]))));
    pm = fmaxf(pm, __shfl_xor(pm, 16));
    pm = fmaxf(pm, __shfl_xor(pm, 32));

    if (!__all(pm <= mr + 8.0f)) {       // defer-max: rescale rarely
      float mnew = fmaxf(mr, pm);
      float scl = __expf(mr - mnew);
      mr = mnew;
      lrp *= scl;
      float s0 = __shfl(scl, 4 * g + 0);
      float s1 = __shfl(scl, 4 * g + 1);
      float s2 = __shfl(scl, 4 * g + 2);
      float s3 = __shfl(scl, 4 * g + 3);
#pragma unroll
      for (int cs = 0; cs < 8; ++cs) {
        o[cs][0] *= s0; o[cs][1] *= s1; o[cs][2] *= s2; o[cs][3] *= s3;
      }
    }

    // ---- exp + pack + LDS transpose to A-frag layout ----
#pragma unroll
    for (int sub = 0; sub < 4; ++sub) {
      float p0 = __expf(sT[sub][0] - mr);
      float p1 = __expf(sT[sub][1] - mr);
      float p2 = __expf(sT[sub][2] - mr);
      float p3 = __expf(sT[sub][3] - mr);
      lrp += (p0 + p1) + (p2 + p3);
      unsigned pk0, pk1;
      asm("v_cvt_pk_bf16_f32 %0, %1, %2" : "=v"(pk0) : "v"(p0), "v"(p1));
      asm("v_cvt_pk_bf16_f32 %0, %1, %2" : "=v"(pk1) : "v"(p2), "v"(p3));
      int c = (2 * sub + (g >> 1)) ^ (lq & 7);
      *(uint2*)(pbuf + lq * 128 + c * 16 + (g & 1) * 8) = make_uint2(pk0, pk1);
    }

    asm volatile("s_waitcnt lgkmcnt(0)" ::: "memory");
    __builtin_amdgcn_sched_barrier(0);

    bf16x8 pa0 = *(const bf16x8*)(pbuf + lq * 128 + ((g ^ (lq & 7)) * 16));
    bf16x8 pa1 = *(const bf16x8*)(pbuf + lq * 128 + (((4 + g) ^ (lq & 7)) * 16));

    // ---- PV ----
#pragma unroll
    for (int cs = 0; cs < 8; ++cs) {
      int drow = cs * 16 + lq;
      const char* vb = vbase + drow * 128;
      int s0i = g ^ (drow & 7);
      int s1i = (4 + g) ^ (drow & 7);
      bf16x8 v0 = *(const bf16x8*)(vb + s0i * 16);
      bf16x8 v1 = *(const bf16x8*)(vb + s1i * 16);
      o[cs] = __builtin_amdgcn_mfma_f32_16x16x32_bf16(pa0, v0, o[cs], 0, 0, 0);
      o[cs] = __builtin_amdgcn_mfma_f32_16x16x32_bf16(pa1, v1, o[cs], 0, 0, 0);
    }

    __syncthreads();  // single drain per iteration (covers next-tile stage)
    buf ^= 1;
  }

  // ---- final l reduction + store ----
  lrp += __shfl_xor(lrp, 16);
  lrp += __shfl_xor(lrp, 32);
  float inv = 1.0f / lrp;
  float invr[4];
  invr[0] = __shfl(inv, 4 * g + 0);
  invr[1] = __shfl(inv, 4 * g + 1);
  invr[2] = __shfl(inv, 4 * g + 2);
  invr[3] = __shfl(inv, 4 * g + 3);
#pragma unroll
  for (int cs = 0; cs < 8; ++cs)
#pragma unroll
    for (int r = 0; r < 4; ++r) {
      int row = qb + w * 16 + 4 * g + r;
      attn[(size_t)(b * 1024 + row) * 4096 + h * 128 + cs * 16 + lq] =
          f2bf(o[cs][r] * invr[r]);
    }
}

// ---------------- launcher ----------------
extern "C" void kernel_launch(void* const* d_in, const int* in_sizes, int n_in,
                              void* d_out, int out_size, void* d_ws, size_t ws_size,
                              hipStream_t stream) {
  const float* x    = (const float*)d_in[0];
  const float* vis  = (const float*)d_in[1];
  const float* wq   = (const float*)d_in[2];
  const float* wk   = (const float*)d_in[3];
  const float* wv   = (const float*)d_in[4];
  const float* wo   = (const float*)d_in[5];
  const float* wvkv = (const float*)d_in[6];
  const float* cosT = (const float*)d_in[7];
  const float* sinT = (const float*)d_in[8];
  float* out = (float*)d_out;
  char* ws = (char*)d_ws;

  size_t off = 0;
  auto alloc = [&](size_t b) { size_t r = off; off += (b + 255) & ~(size_t)255; return r; };
  unsigned short* wqkvb = (unsigned short*)(ws + alloc((size_t)5120 * 4096 * 2));  // wq|wk|wv
  unsigned short* wob   = (unsigned short*)(ws + alloc((size_t)4096 * 4096 * 2));
  unsigned short* wvkvb = (unsigned short*)(ws + alloc((size_t)1024 * 768 * 2));
  unsigned short* visb  = (unsigned short*)(ws + alloc((size_t)512 * 768 * 2));
  unsigned short* xb    = (unsigned short*)(ws + alloc((size_t)2048 * 4096 * 2));
  unsigned short* qkv   = (unsigned short*)(ws + alloc((size_t)2048 * 5120 * 2));
  unsigned short* vkvb  = (unsigned short*)(ws + alloc((size_t)512 * 1024 * 2));
  unsigned short* kall  = (unsigned short*)(ws + alloc((size_t)8 * 1280 * 128 * 2));
  unsigned short* vt    = (unsigned short*)(ws + alloc((size_t)8 * 128 * 1280 * 2));
  unsigned short* attnb = xb;  // x is dead after the QKV projection; reuse
  if (ws_size < off) return;

  auto cast = [&](const float* src, unsigned short* dst, size_t n) {
    int n4 = (int)(n / 4);
    int grid = (n4 + 255) / 256;
    if (grid > 1280) grid = 1280;
    k_cast<<<dim3(grid), dim3(256), 0, stream>>>(src, dst, n4);
  };
  cast(x, xb, (size_t)2048 * 4096);
  cast(wq, wqkvb, (size_t)4096 * 4096);
  cast(wk, wqkvb + (size_t)4096 * 4096, (size_t)512 * 4096);
  cast(wv, wqkvb + (size_t)4608 * 4096, (size_t)512 * 4096);
  cast(wo, wob, (size_t)4096 * 4096);
  cast(wvkv, wvkvb, (size_t)1024 * 768);
  cast(vis, visb, (size_t)512 * 768);

  // fused QKV projection: [2048][5120]
  k_gemm_bt<unsigned short><<<dim3(16, 40), dim3(256), 0, stream>>>(xb, wqkvb, qkv, 2048, 5120, 4096);
  k_gemm_bt<unsigned short><<<dim3(4, 8), dim3(256), 0, stream>>>(visb, wvkvb, vkvb, 512, 1024, 768);

  k_rope_q<<<dim3(16384), dim3(256), 0, stream>>>(qkv, cosT, sinT);
  k_build_k<<<dim3(2560), dim3(256), 0, stream>>>(qkv, vkvb, cosT, sinT, kall);
  k_build_v<<<dim3(5120), dim3(256), 0, stream>>>(qkv, vkvb, vt);

  k_attn<<<dim3(16, 32, 2), dim3(256), 0, stream>>>(qkv, kall, vt, attnb);

  k_gemm_bt<float><<<dim3(16, 32), dim3(256), 0, stream>>>(attnb, wob, out, 2048, 4096, 4096);
}